// Round 9
// baseline (109.253 us; speedup 1.0000x reference)
//
#include <hip/hip_runtime.h>

// Fast HW transcendentals (v_exp_f32 / v_log_f32 / v_rcp_f32), with fallbacks.
#if __has_builtin(__builtin_amdgcn_exp2f)
#define FAST_EXP2(x) __builtin_amdgcn_exp2f(x)
#else
#define FAST_EXP2(x) exp2f(x)
#endif
#if __has_builtin(__builtin_amdgcn_logf)
#define FAST_LOG2(x) __builtin_amdgcn_logf(x)
#else
#define FAST_LOG2(x) log2f(x)
#endif
#if __has_builtin(__builtin_amdgcn_rcpf)
#define FAST_RCP(x) __builtin_amdgcn_rcpf(x)
#else
#define FAST_RCP(x) (1.0f / (x))
#endif

#define LOG2E 1.44269504088896340736f

// Compiler-generated vector math ONLY (rounds 4-6 condemned inline-asm v_pk_*).
typedef float v2f __attribute__((ext_vector_type(2)));

__device__ __forceinline__ v2f v2fma(v2f a, v2f b, v2f c) {
    return __builtin_elementwise_fma(a, b, c);
}

// tanh on a pair; per-element math/order identical to rounds 1-3/7/8.
__device__ __forceinline__ v2f fast_tanh2(v2f v) {
    v2f t = v * (v2f)(2.0f * LOG2E);
    v2f e;
    e.x = FAST_EXP2(t.x);
    e.y = FAST_EXP2(t.y);
    v2f d = e + (v2f)(1.0f);
    v2f r;
    r.x = FAST_RCP(d.x);
    r.y = FAST_RCP(d.y);
    return v2fma((v2f)(-2.0f), r, (v2f)(1.0f));
}

__device__ __forceinline__ float fast_sigmoid(float v) {
    return FAST_RCP(1.0f + FAST_EXP2(-v * LOG2E));
}

#define ROWS 4

// R9 experiment: k-sliced REGISTER-RESIDENT weights.
// Evidence: R3(global/SGPR)==R7(LDS)==R8(+row-loop) ~27us with VALUBusy only
// 75-79% -> ~25% issue-idle = operand-fetch stalls (the fully-unrolled body
// re-reads ~90 weight operands per row from LDS/SMEM). Fix: make k a REAL
// loop; per k-iteration load network k's 79 weights into VGPRs ONCE, then the
// ROWS=4 row bodies are memory-free pure VALU/trans. Math bit-identical.
__global__ __launch_bounds__(256) void subsurf_kernel(
    const float* __restrict__ x, const float* __restrict__ S1,
    const float* __restrict__ W1, const float* __restrict__ b1,
    const float* __restrict__ W2, const float* __restrict__ b2,
    const float* __restrict__ W3, const float* __restrict__ b3,
    float* __restrict__ out, int n)
{
    // LDS: 3 slices of 80 floats (320 B, 16B-aligned), one per network k:
    //   [0..24) W1k  [24..60) W2k  [60..66) W3k  [66..72) b1k  [72..78) b2k
    //   [78] b3k  [79] pad
    __shared__ __align__(16) float w[240];
    int t = threadIdx.x;
    if (t < 240) {
        int slice = t / 80;       // k
        int r = t - slice * 80;
        float v = 0.0f;
        if (r < 24)      v = W1[slice * 24 + r];
        else if (r < 60) v = W2[slice * 36 + (r - 24)];
        else if (r < 66) v = W3[slice * 6 + (r - 60)];
        else if (r < 72) v = b1[slice * 6 + (r - 66)];
        else if (r < 78) v = b2[slice * 6 + (r - 72)];
        else if (r < 79) v = b3[slice];
        w[t] = v;  // r==79 pad
    }
    __syncthreads();

    int base = blockIdx.x * (256 * ROWS) + t;

    // Load all ROWS rows' inputs up front (coalesced; clamped for the tail
    // block, stores guarded below).
    float4 xv[ROWS];
    float s1v[ROWS];
    #pragma unroll
    for (int j = 0; j < ROWS; ++j) {
        int i = base + j * 256;
        int ic = i < n ? i : (n - 1);
        xv[j] = ((const float4*)x)[ic];
        s1v[j] = S1[ic];
    }

    float p_S1max[ROWS], p_ks[ROWS], p_n[ROWS];

    #pragma unroll 1   // REAL loop: only one network's weights live at a time
    for (int k = 0; k < 3; ++k) {
        const float* s = w + k * 80;
        const v2f* w1p = (const v2f*)(s);        // [d*3 + jp]
        const v2f* w2p = (const v2f*)(s + 24);   // [ww*3 + jp]
        const v2f* w3p = (const v2f*)(s + 60);
        const v2f* b1p = (const v2f*)(s + 66);
        const v2f* b2p = (const v2f*)(s + 72);

        // Hoist network k's weights into registers (once per 4 rows).
        v2f w1r[12];
        #pragma unroll
        for (int q = 0; q < 12; ++q) w1r[q] = w1p[q];
        v2f w2r[18];
        #pragma unroll
        for (int q = 0; q < 18; ++q) w2r[q] = w2p[q];
        v2f w3v[3];
        #pragma unroll
        for (int q = 0; q < 3; ++q) w3v[q] = w3p[q];
        v2f b1r[3];
        #pragma unroll
        for (int q = 0; q < 3; ++q) b1r[q] = b1p[q];
        v2f b2r[3];
        #pragma unroll
        for (int q = 0; q < 3; ++q) b2r[q] = b2p[q];
        float b3k = s[78];

        // Bit-match numpy f32 constants (compiler folds the f32 subtractions).
        float low_k   = (k == 0) ? 100.0f : 0.01f;
        float range_k = (k == 0) ? (500.0f - 100.0f)
                                 : ((k == 1) ? (100.0f - 0.01f) : (10.0f - 0.01f));

        #pragma unroll
        for (int j = 0; j < ROWS; ++j) {
            float xs[4] = {xv[j].x, xv[j].y, xv[j].z, xv[j].w};

            float h1[6];
            #pragma unroll
            for (int jp = 0; jp < 3; ++jp) {
                v2f acc = b1r[jp];
                #pragma unroll
                for (int d = 0; d < 4; ++d)
                    acc = v2fma((v2f)(xs[d]), w1r[d * 3 + jp], acc);
                v2f th = fast_tanh2(acc);
                h1[2 * jp]     = th.x;
                h1[2 * jp + 1] = th.y;
            }
            float h2[6];
            #pragma unroll
            for (int jp = 0; jp < 3; ++jp) {
                v2f acc = b2r[jp];
                #pragma unroll
                for (int ww = 0; ww < 6; ++ww)
                    acc = v2fma((v2f)(h1[ww]), w2r[ww * 3 + jp], acc);
                v2f th = fast_tanh2(acc);
                h2[2 * jp]     = th.x;
                h2[2 * jp + 1] = th.y;
            }
            // Layer 3: scalar sequential order (bit-matches prior rounds).
            float y = b3k;
            y = fmaf(h2[0], w3v[0].x, y);
            y = fmaf(h2[1], w3v[0].y, y);
            y = fmaf(h2[2], w3v[1].x, y);
            y = fmaf(h2[3], w3v[1].y, y);
            y = fmaf(h2[4], w3v[2].x, y);
            y = fmaf(h2[5], w3v[2].y, y);
            float val = fmaf(range_k, fast_sigmoid(y), low_k);

            if (k == 0)      p_S1max[j] = val;   // wave-uniform branch on k
            else if (k == 1) p_ks[j]    = val;
            else             p_n[j]     = val;
        }
    }

    #pragma unroll
    for (int j = 0; j < ROWS; ++j) {
        int i = base + j * 256;
        float S1max = p_S1max[j], ks = p_ks[j], nexp = p_n[j];
        // (S1/S1max)^n in log2 domain: handles S1==0 (log2->-inf, exp2->0).
        float lr = FAST_LOG2(s1v[j]) - FAST_LOG2(S1max);
        float flow = ks * FAST_EXP2(nexp * lr);
        flow = fminf(fmaxf(flow, 0.0f), S1max);
        if (i < n) out[i] = flow;
    }
}

extern "C" void kernel_launch(void* const* d_in, const int* in_sizes, int n_in,
                              void* d_out, int out_size, void* d_ws, size_t ws_size,
                              hipStream_t stream) {
    const float* x  = (const float*)d_in[0];
    const float* S1 = (const float*)d_in[1];
    const float* W1 = (const float*)d_in[2];
    const float* b1 = (const float*)d_in[3];
    const float* W2 = (const float*)d_in[4];
    const float* b2 = (const float*)d_in[5];
    const float* W3 = (const float*)d_in[6];
    const float* b3 = (const float*)d_in[7];
    float* out = (float*)d_out;

    int n = out_size;  // N = 2,000,000 rows, one output per row
    int rows_per_block = 256 * ROWS;
    int grid = (n + rows_per_block - 1) / rows_per_block;
    subsurf_kernel<<<grid, 256, 0, stream>>>(x, S1, W1, b1, W2, b2, W3, b3, out, n);
}

// Round 10
// 109.014 us; speedup vs baseline: 1.0022x; 1.0022x over previous
//
#include <hip/hip_runtime.h>

// Fast HW transcendentals (v_exp_f32 / v_log_f32 / v_rcp_f32), with fallbacks.
#if __has_builtin(__builtin_amdgcn_exp2f)
#define FAST_EXP2(x) __builtin_amdgcn_exp2f(x)
#else
#define FAST_EXP2(x) exp2f(x)
#endif
#if __has_builtin(__builtin_amdgcn_logf)
#define FAST_LOG2(x) __builtin_amdgcn_logf(x)
#else
#define FAST_LOG2(x) log2f(x)
#endif
#if __has_builtin(__builtin_amdgcn_rcpf)
#define FAST_RCP(x) __builtin_amdgcn_rcpf(x)
#else
#define FAST_RCP(x) (1.0f / (x))
#endif

#define LOG2E 1.44269504088896340736f

// Compiler-generated vector math ONLY (rounds 4-6 condemned inline-asm v_pk_*).
typedef float v2f __attribute__((ext_vector_type(2)));

__device__ __forceinline__ v2f v2fma(v2f a, v2f b, v2f c) {
    return __builtin_elementwise_fma(a, b, c);
}

// R10: the kernel is trans-pipe-bound (R7/R8/R9 structural changes all flat;
// invariant = 81 trans/row). Reduce trans count via rcp ganging:
// 1/a,1/b = t=rcp(a*b); t*b, t*a  (2 trans -> 1 trans + 3 full-rate).
// tanh pair: 2 rcp -> 1. Numerics: few-ulp perturbation; d.x*d.y overflow
// needs |2vx+2vy| > 88*ln2 — unreachable; in that limit result saturates to
// the correct +1 anyway.
__device__ __forceinline__ v2f fast_tanh2(v2f v) {
    v2f t = v * (v2f)(2.0f * LOG2E);
    v2f e;
    e.x = FAST_EXP2(t.x);
    e.y = FAST_EXP2(t.y);
    v2f d = e + (v2f)(1.0f);
    float tp = FAST_RCP(d.x * d.y);
    v2f r;
    r.x = tp * d.y;
    r.y = tp * d.x;
    return v2fma((v2f)(-2.0f), r, (v2f)(1.0f));
}

// R7 structure: 1 row/thread, LDS-staged weights, fully-unrolled k.
// Change vs R7: tanh rcp-gang + the three sigmoids' rcps ganged (3 -> 1).
__global__ __launch_bounds__(256) void subsurf_kernel(
    const float* __restrict__ x, const float* __restrict__ S1,
    const float* __restrict__ W1, const float* __restrict__ b1,
    const float* __restrict__ W2, const float* __restrict__ b2,
    const float* __restrict__ W3, const float* __restrict__ b3,
    float* __restrict__ out, int n)
{
    // Layout: W1[0..72) b1[72..90) W2[90..198) b2[198..216) W3[216..234) b3[234..237)
    __shared__ __align__(16) float w[240];
    int t = threadIdx.x;
    if (t < 72)       w[t] = W1[t];
    else if (t < 90)  w[t] = b1[t - 72];
    else if (t < 198) w[t] = W2[t - 90];
    else if (t < 216) w[t] = b2[t - 198];
    else if (t < 234) w[t] = W3[t - 216];
    else if (t < 237) w[t] = b3[t - 234];
    __syncthreads();

    int i = blockIdx.x * blockDim.x + t;
    if (i >= n) return;

    const v2f* W1p = (const v2f*)(w + 0);    // [(k*4+d)*3 + jp]
    const v2f* b1p = (const v2f*)(w + 72);   // [k*3 + jp]
    const v2f* W2p = (const v2f*)(w + 90);   // [(k*6+ww)*3 + jp]
    const v2f* b2p = (const v2f*)(w + 198);  // [k*3 + jp]
    const float* W3s = w + 216;              // [k*6 + v]
    const float* b3s = w + 234;              // [k]

    // Coalesced 16B/lane load of the 4 features.
    float4 xv = ((const float4*)x)[i];
    float xs[4] = {xv.x, xv.y, xv.z, xv.w};
    float s1 = S1[i];

    // Bit-match numpy f32 constant arithmetic for lows / (highs - lows).
    const float lows[3]   = {100.0f, 0.01f, 0.01f};
    const float ranges[3] = {500.0f - 100.0f, 100.0f - 0.01f, 10.0f - 0.01f};

    float ys[3];
    #pragma unroll
    for (int k = 0; k < 3; ++k) {
        float h1[6];
        #pragma unroll
        for (int jp = 0; jp < 3; ++jp) {
            v2f acc = b1p[k * 3 + jp];
            #pragma unroll
            for (int d = 0; d < 4; ++d)
                acc = v2fma((v2f)(xs[d]), W1p[(k * 4 + d) * 3 + jp], acc);
            v2f th = fast_tanh2(acc);
            h1[2 * jp]     = th.x;
            h1[2 * jp + 1] = th.y;
        }
        float h2[6];
        #pragma unroll
        for (int jp = 0; jp < 3; ++jp) {
            v2f acc = b2p[k * 3 + jp];
            #pragma unroll
            for (int ww = 0; ww < 6; ++ww)
                acc = v2fma((v2f)(h1[ww]), W2p[(k * 6 + ww) * 3 + jp], acc);
            v2f th = fast_tanh2(acc);
            h2[2 * jp]     = th.x;
            h2[2 * jp + 1] = th.y;
        }
        // Layer 3: scalar sequential order.
        float y = b3s[k];
        #pragma unroll
        for (int v = 0; v < 6; ++v)
            y = fmaf(h2[v], W3s[k * 6 + v], y);
        ys[k] = y;
    }

    // Ganged sigmoid trio: s_k = 1/d_k via one rcp of the triple product.
    float d0 = 1.0f + FAST_EXP2(-ys[0] * LOG2E);
    float d1 = 1.0f + FAST_EXP2(-ys[1] * LOG2E);
    float d2 = 1.0f + FAST_EXP2(-ys[2] * LOG2E);
    float p01 = d0 * d1;
    float tp = FAST_RCP(p01 * d2);
    float sg0 = tp * (d1 * d2);
    float sg1 = tp * (d0 * d2);
    float sg2 = tp * p01;

    float S1max = fmaf(ranges[0], sg0, lows[0]);
    float ks    = fmaf(ranges[1], sg1, lows[1]);
    float nexp  = fmaf(ranges[2], sg2, lows[2]);

    // (S1/S1max)^n in log2 domain: handles S1==0 (log2->-inf, exp2->0).
    float lr = FAST_LOG2(s1) - FAST_LOG2(S1max);
    float flow = ks * FAST_EXP2(nexp * lr);
    flow = fminf(fmaxf(flow, 0.0f), S1max);
    out[i] = flow;
}

extern "C" void kernel_launch(void* const* d_in, const int* in_sizes, int n_in,
                              void* d_out, int out_size, void* d_ws, size_t ws_size,
                              hipStream_t stream) {
    const float* x  = (const float*)d_in[0];
    const float* S1 = (const float*)d_in[1];
    const float* W1 = (const float*)d_in[2];
    const float* b1 = (const float*)d_in[3];
    const float* W2 = (const float*)d_in[4];
    const float* b2 = (const float*)d_in[5];
    const float* W3 = (const float*)d_in[6];
    const float* b3 = (const float*)d_in[7];
    float* out = (float*)d_out;

    int n = out_size;  // N = 2,000,000 rows, one output per row
    int block = 256;
    int grid = (n + block - 1) / block;
    subsurf_kernel<<<grid, block, 0, stream>>>(x, S1, W1, b1, W2, b2, W3, b3, out, n);
}